// Round 9
// baseline (237.326 us; speedup 1.0000x reference)
//
#include <hip/hip_runtime.h>
#include <math.h>

// LSTM B=1024,T=512,IN=16,H=64,OUT=8, gates i,f,g,o.
// R21: QUAD-PAIRED BT=4. R17-R20 established wall = per-SIMD issue volume
// (790cyc/step: MFMA 300 + VALU 446 = 94%). Trans at floor (6/wave), but
// MFMA carried 8x col replication (16 cols = 2 batches). R14's BT=4 flat
// failed because pairing died (m-bits exhausted, trans 6->10). Fix: move
// the gate-pair axis to a q-bit:
//   - B cols = 4 b x 4 replicas (b=m&3, rho=m>>2).
//   - A rows MIX gate-halves: rows (r>>2)&1==0 carry f|i, ==1 carry g|o;
//     j(r) = 8w + 4*(r>>3) + (r&3). Lane gate-half = q&1 (compile-time!),
//     j = 8w + 4*(q>>1) + rho. Pair exchange = lane^16 via ds_swizzle
//     0x401F. Trans stays 6; the h1?: selects on u1/u2 disappear.
//   - MFMA 8 -> 4 per wave-step (2 mixed tiles FG,IO x 2 K-halves).
//   - 512-thr block (8 waves, 8-j slice each), grid 256, 1 block/CU,
//     2 waves/SIMD (same occupancy). Weight regs halve (6 tiles).
// xw: 4-step chunks (16 burst cols = 4t x 4b all real), 2 burst MFMAs +
// 4 float2 writes spread across the chunk's steps; pairs preloaded 1 step
// early; same-wave j-slice alignment keeps write->read ordered.
// Kept: scales folded (f,i,o x -L2E; g x +L2E2; cs=L2E2*c), dump-row
// unconditional h-write, breadth-first MFMAs, setprio, 1 barrier/step.

#define LSTM_T 512
#define LSTM_IN 16
#define LSTM_H 64
#define LSTM_OUT 8
#define BT 4
#define HSTRIDE 80    // halves per row; rows 0..3 = real b, 4..7 = dump
#define HPSTR 640     // parity stride in halves = 8*HSTRIDE
#define XSTR 67       // float2 stride per slot row (67*2%32=6: ~4-way max)
#define XWSZ 2144     // 32*XSTR

#define L2E   1.44269504088896340736f
#define L2E2  2.88539008177792681472f

typedef _Float16 half8  __attribute__((ext_vector_type(8)));
typedef float    floatx4 __attribute__((ext_vector_type(4)));

static __device__ __forceinline__ float fast_rcp(float x) { return __builtin_amdgcn_rcpf(x); }
static __device__ __forceinline__ float fast_exp2(float x) { return __builtin_amdgcn_exp2f(x); }
static __device__ __forceinline__ float sigm2(float p) { return fast_rcp(1.0f + fast_exp2(-p)); }
static __device__ __forceinline__ void pin4(int4& v) {
    asm volatile("" : "+v"(v.x), "+v"(v.y), "+v"(v.z), "+v"(v.w));
}
static __device__ __forceinline__ void pinf4(float4& v) {
    asm volatile("" : "+v"(v.x), "+v"(v.y), "+v"(v.z), "+v"(v.w));
}
static __device__ __forceinline__ void lite_barrier() {
    asm volatile("s_waitcnt lgkmcnt(0)\n\ts_barrier" ::: "memory");
}
static __device__ __forceinline__ unsigned pk2h(float a, float b) {
    return __builtin_bit_cast(unsigned, __builtin_amdgcn_cvt_pkrtz(a, b));
}
static __device__ __forceinline__ half8 to_h8(float4 a, float4 b) {
    uint4 u = make_uint4(pk2h(a.x, a.y), pk2h(a.z, a.w), pk2h(b.x, b.y), pk2h(b.z, b.w));
    return __builtin_bit_cast(half8, u);
}
static __device__ __forceinline__ int4 cvt8h(float4 a, float4 b) {
    return __builtin_bit_cast(int4, to_h8(a, b));
}
static __device__ __forceinline__ float4 ld4(const float* p) {
    return *reinterpret_cast<const float4*>(p);
}
static __device__ __forceinline__ float4 scl4(float4 v, float s) {
    return make_float4(s * v.x, s * v.y, s * v.z, s * v.w);
}
static __device__ __forceinline__ float sel4(floatx4 v, bool r0, bool r1) {
    float lo = r0 ? v[1] : v[0];
    float hi = r0 ? v[3] : v[2];
    return r1 ? hi : lo;
}
// lane^16 exchange: ds_swizzle BitMode xor=16 (within 32-lane groups,
// bit4 stays inside the group -> global lane^16).
static __device__ __forceinline__ float swz16(float v) {
    int r = __builtin_amdgcn_ds_swizzle(__builtin_bit_cast(int, v), 0x401F);
    return __builtin_bit_cast(float, r);
}

#define MF(A_, B_, C_) __builtin_amdgcn_mfma_f32_16x16x32_f16( \
        __builtin_bit_cast(half8, A_), (B_), (C_), 0, 0, 0)

__global__ __launch_bounds__(512, 2)
void lstm_mfma_kernel(const float* __restrict__ x,
                      const float* __restrict__ W_ih,
                      const float* __restrict__ W_hh,
                      const float* __restrict__ b_ih,
                      const float* __restrict__ b_hh,
                      const float* __restrict__ W_fc,
                      const float* __restrict__ b_fc,
                      float* __restrict__ out) {
    const int tid   = threadIdx.x;
    const int lane  = tid & 63;
    const int w     = tid >> 6;        // wave -> j-slice [8w, 8w+8)
    const int q     = lane >> 4;
    const int m     = lane & 15;
    const int b     = m & 3;           // real batch 0..3
    const int rho   = m >> 2;          // C reg select
    const bool r0   = (rho & 1) != 0;
    const bool r1   = (rho & 2) != 0;
    const int gh    = q & 1;           // gate-half: 0 = f/i, 1 = g/o
    const int jj    = q >> 1;
    const int jmine = 8 * w + 4 * jj + rho;
    const int bbase = blockIdx.x * BT;

    // half gh=0: act1 = sigma(f); gh=1: act1 = L2E2*tanh(g)
    const float a1 = gh ? L2E2 : 0.0f;
    const float b1 = gh ? (-2.0f * L2E2) : 1.0f;

    __shared__ __align__(16)  float2   xwbuf[2][XWSZ];           // xw chunks
    __shared__ __align__(128) _Float16 hbuf[2][2 * BT][HSTRIDE]; // h + dump
    __shared__ __align__(16)  float    hfin[BT][LSTM_H];         // final h

    // ---- weights as pinned fp16 A-fragments (mixed-gate rows) ----
    // A row r: gate-half ghr=(r>>2)&1, jl = 4*(r>>3)+(r&3); lane loads row m.
    const int  ghr = (m >> 2) & 1;
    const int  jl  = 4 * (m >> 3) + (m & 3);
    const int  gFG = ghr ? 2 : 1;           // f=1, g=2
    const int  gIO = ghr ? 3 : 0;           // i=0, o=3
    const float sFG = ghr ? L2E2 : -L2E;
    const int growFG = gFG * 64 + 8 * w + jl;
    const int growIO = gIO * 64 + 8 * w + jl;
    int4 AhFG[2], AhIO[2], AxFG, AxIO;
    #pragma unroll
    for (int c = 0; c < 2; ++c) {
        const float* s1 = W_hh + growFG * LSTM_H + 32 * c + 8 * q;
        AhFG[c] = cvt8h(scl4(ld4(s1), sFG), scl4(ld4(s1 + 4), sFG));
        pin4(AhFG[c]);
        const float* s2 = W_hh + growIO * LSTM_H + 32 * c + 8 * q;
        AhIO[c] = cvt8h(scl4(ld4(s2), -L2E), scl4(ld4(s2 + 4), -L2E));
        pin4(AhIO[c]);
    }
    {
        float4 za = make_float4(0.f, 0.f, 0.f, 0.f), zb = za;
        float4 xa = za, xb = za, ya = za, yb = za;
        if (q < 2) {
            const float* s1 = W_ih + growFG * LSTM_IN + 8 * q;
            xa = ld4(s1); xb = ld4(s1 + 4);
            const float* s2 = W_ih + growIO * LSTM_IN + 8 * q;
            ya = ld4(s2); yb = ld4(s2 + 4);
        }
        AxFG = cvt8h(scl4(xa, sFG), scl4(xb, sFG));  pin4(AxFG);
        AxIO = cvt8h(scl4(ya, -L2E), scl4(yb, -L2E)); pin4(AxIO);
        (void)za; (void)zb;
    }
    // burst bias C-in (by C rows 4q+p): gate-half = q&1, j = 8w+4*(q>>1)+p
    float4 bFG4, bIO4;
    {
        const float scq = (q & 1) ? L2E2 : -L2E;
        const int gb1 = ((q & 1) ? 2 : 1) * 64 + 8 * w + 4 * (q >> 1);
        float4 bi = ld4(b_ih + gb1), bh = ld4(b_hh + gb1);
        bFG4 = make_float4(scq * (bi.x + bh.x), scq * (bi.y + bh.y),
                           scq * (bi.z + bh.z), scq * (bi.w + bh.w));
        pinf4(bFG4);
        const int gb2 = ((q & 1) ? 3 : 0) * 64 + 8 * w + 4 * (q >> 1);
        float4 ci = ld4(b_ih + gb2), ch = ld4(b_hh + gb2);
        bIO4 = make_float4(-L2E * (ci.x + ch.x), -L2E * (ci.y + ch.y),
                           -L2E * (ci.z + ch.z), -L2E * (ci.w + ch.w));
        pinf4(bIO4);
    }
    const floatx4 bFGv = __builtin_bit_cast(floatx4, bFG4);
    const floatx4 bIOv = __builtin_bit_cast(floatx4, bIO4);

    float4 zc4 = make_float4(0.f, 0.f, 0.f, 0.f);
    pinf4(zc4);
    const floatx4 zc = __builtin_bit_cast(floatx4, zc4);

    // ---- LDS pointers ----
    // xw slot row = k*8 + b*2 + gh; col = j.
    const float2* xwr = &xwbuf[0][(b * 2 + gh) * XSTR + jmine];
    float2*       xww = &xwbuf[0][(8 * (m >> 2) + 2 * (m & 3) + (q & 1)) * XSTR
                                  + 8 * w + 4 * (q >> 1)];
    const _Float16* hrp = &hbuf[0][b][8 * q];
    _Float16*       hwp = &hbuf[0][gh ? 4 + b : b][jmine];

    // ---- zero hbuf[0] (h_{-1}=0): 8 rows * 80 halves = 320 dwords ----
    if (tid < 320) reinterpret_cast<int*>(&hbuf[0][0][0])[tid] = 0;

    // ---- burst x pointer: lane covers (b=m&3, t-in-chunk=m>>2) ----
    const float* xpb = x + (size_t)(bbase + b) * LSTM_T * LSTM_IN
                         + (size_t)(m >> 2) * LSTM_IN + 8 * q;
    float4 Xb0 = make_float4(0.f, 0.f, 0.f, 0.f), Xb1 = Xb0;
    if (q < 2) { Xb0 = ld4(xpb); Xb1 = ld4(xpb + 4); }   // chunk 0

#define WX(BUF, P_) xww[(BUF) * XWSZ + (P_)] = make_float2(aFGx[P_], aIOx[P_]);

    // ---- prologue: chunk0 -> buf0 ----
    floatx4 aFGx, aIOx;
    half8 xfb;
    {
        half8 x0 = to_h8(Xb0, Xb1);
        aFGx = MF(AxFG, x0, bFGv);
        aIOx = MF(AxIO, x0, bIOv);
        WX(0, 0) WX(0, 1) WX(0, 2) WX(0, 3)
    }
    if (q < 2) {   // x for chunk 1
        Xb0 = ld4(xpb + 4 * LSTM_IN);
        Xb1 = ld4(xpb + 4 * LSTM_IN + 4);
    }
    __syncthreads();   // hbuf zeros + chunk0 visible

    float2 xwc = xwr[0];             // k=0, buf0
    float cs = 0.0f, hreg = 0.0f;    // cs = L2E2*c (gh=0 lanes valid)

// PK = hbuf parity (literal), KN = next step's k (literal),
// NCB = next step's chunk buf (literal). __VA_ARGS__ = spread burst op.
#define STEP_CORE(PK, KN, NCB, ...)                                             \
    {                                                                           \
        half8 bh0 = *reinterpret_cast<const half8*>(hrp + (PK) * HPSTR);        \
        half8 bh1 = *reinterpret_cast<const half8*>(hrp + (PK) * HPSTR + 32);   \
        __VA_ARGS__                                                             \
        float2 xwn = xwr[(NCB) * XWSZ + (KN) * 8 * XSTR];                       \
        floatx4 accFG = MF(AhFG[0], bh0, zc);                                   \
        floatx4 accIO = MF(AhIO[0], bh0, zc);                                   \
        accFG = MF(AhFG[1], bh1, accFG);                                        \
        accIO = MF(AhIO[1], bh1, accIO);                                        \
        __builtin_amdgcn_s_setprio(1);                                          \
        float u1 = sel4(accFG, r0, r1) + xwc.x;                                 \
        float e1 = fast_exp2(u1);                                               \
        float u2 = sel4(accIO, r0, r1) + xwc.y;                                 \
        float act1 = fmaf(b1, fast_rcp(1.0f + e1), a1);                         \
        float e2 = fast_exp2(u2);                                               \
        float act2 = fast_rcp(1.0f + e2);                                       \
        float g_in = swz16(act1);    /* gh0 gets L2E2*tanh(g) */                \
        float o_in = swz16(act2);    /* gh0 gets sigma(o) */                    \
        cs = fmaf(act1, cs, act2 * g_in);                                       \
        float E  = fast_exp2(cs);                                               \
        float r_ = fast_rcp(1.0f + E);                                          \
        float n2o = -2.0f * o_in;                                               \
        hreg = fmaf(n2o, r_, o_in);  /* o * tanh(c) */                          \
        hwp[((PK) ^ 1) * HPSTR] = (_Float16)hreg;   /* gh1 -> dump rows */      \
        __builtin_amdgcn_s_setprio(0);                                          \
        lite_barrier();                                                         \
        xwc = xwn;                                                              \
    }

    for (int t8 = 0; t8 < LSTM_T; t8 += 8) {
        const bool mA = t8 + 4  < LSTM_T;   // produce chunk c+1 (buf1)
        const bool mB = t8 + 8  < LSTM_T;   // produce chunk c+2 (buf0)
        const bool xB = t8 + 12 < LSTM_T;   // load x for chunk c+3
        // chunk A: consume buf0, produce buf1
        STEP_CORE(0, 1, 0,
            { if (mA) { xfb = to_h8(Xb0, Xb1); aFGx = MF(AxFG, xfb, bFGv); } })
        STEP_CORE(1, 2, 0, { if (mA) { aIOx = MF(AxIO, xfb, bIOv); } })
        STEP_CORE(0, 3, 0, { if (mA) { WX(1, 0) WX(1, 1) } })
        STEP_CORE(1, 0, 1, { if (mA) { WX(1, 2) WX(1, 3) }
            if (q < 2 && mB) { Xb0 = ld4(xpb + (size_t)(t8 + 8) * LSTM_IN);
                               Xb1 = ld4(xpb + (size_t)(t8 + 8) * LSTM_IN + 4); } })
        // chunk B: consume buf1, produce buf0
        STEP_CORE(0, 1, 1,
            { if (mB) { xfb = to_h8(Xb0, Xb1); aFGx = MF(AxFG, xfb, bFGv); } })
        STEP_CORE(1, 2, 1, { if (mB) { aIOx = MF(AxIO, xfb, bIOv); } })
        STEP_CORE(0, 3, 1, { if (mB) { WX(0, 0) WX(0, 1) } })
        STEP_CORE(1, 0, 0, { if (mB) { WX(0, 2) WX(0, 3) }
            if (q < 2 && xB) { Xb0 = ld4(xpb + (size_t)(t8 + 12) * LSTM_IN);
                               Xb1 = ld4(xpb + (size_t)(t8 + 12) * LSTM_IN + 4); } })
    }
#undef STEP_CORE
#undef WX

    // ---- final h (fp32) -> LDS, then FC + sigmoid ----
    if (!gh) hfin[b][jmine] = hreg;   // gh=0 lanes hold valid state
    __syncthreads();

    if (tid < BT * LSTM_OUT) {
        int bb = tid >> 3, o = tid & 7;
        float s = b_fc[o];
        #pragma unroll
        for (int j4 = 0; j4 < LSTM_H / 4; ++j4) {
            float4 wv = ld4(W_fc + o * LSTM_H + 4 * j4);
            float4 hv = *reinterpret_cast<const float4*>(&hfin[bb][4 * j4]);
            s = fmaf(wv.x, hv.x, s);
            s = fmaf(wv.y, hv.y, s);
            s = fmaf(wv.z, hv.z, s);
            s = fmaf(wv.w, hv.w, s);
        }
        out[(size_t)(bbase + bb) * LSTM_OUT + o] = sigm2(s * L2E);
    }
}

extern "C" void kernel_launch(void* const* d_in, const int* in_sizes, int n_in,
                              void* d_out, int out_size, void* d_ws, size_t ws_size,
                              hipStream_t stream) {
    const float* x    = (const float*)d_in[0];
    const float* W_ih = (const float*)d_in[1];
    const float* W_hh = (const float*)d_in[2];
    const float* b_ih = (const float*)d_in[3];
    const float* b_hh = (const float*)d_in[4];
    const float* W_fc = (const float*)d_in[5];
    const float* b_fc = (const float*)d_in[6];
    float* out = (float*)d_out;

    lstm_mfma_kernel<<<1024 / BT, 512, 0, stream>>>(
        x, W_ih, W_hh, b_ih, b_hh, W_fc, b_fc, out);
}

// Round 10
// 230.366 us; speedup vs baseline: 1.0302x; 1.0302x over previous
//
#include <hip/hip_runtime.h>
#include <math.h>

// LSTM B=1024,T=512,IN=16,H=64,OUT=8, gates i,f,g,o.
// R22: QUAD-PAIRED BT=4 + PERMLANE EXCHANGE. R21 halved per-SIMD issue
// (440 of 907 cyc, 48% saturated vs R20's 94%) but regressed because the
// lane^16 exchange used ds_swizzle (LDS pipe, ~130cyc x2, inside the
// lgkm drain). Fix: gate-pair axis -> lane^32 (gh = q>>1) and exchange
// via v_permlane32_swap_b32 (VALU, measured on gfx950):
//   with X=Y=act1, after swap X = gh0-value on ALL lanes, Y = gh1-value
//   on ALL lanes -> canonical sigma(f)/L2E2*tanh(g)/sigma(i)/sigma(o)
//   roles everywhere, ZERO cndmasks, no garbage lanes, no dump rows;
//   all 64 lanes compute true cs/h (pair lanes write same addr, same
//   value -> merge). 1 v_mov + 1 permlane per exchange.
// Remap: jj=q&1, jmine=8w+4jj+rho; A rows ghr=m>>3, jl=4*((m>>2)&1)+
// (m&3); bias rows by (q>>1, 4*(q&1)); xw slot row = dt*8+b*2+(q>>1),
// col = 8w+4*(q&1)+p.
// Kept from R21: BT=4 (16 B-cols = 4 real batches x 4 replicas), MFMA
// 8->4/wave-step (mixed FG,IO tiles x 2 K-halves), 4-step xw chunks
// (2 burst MFMAs + 4 float2 writes spread), 512-thr block, grid 256,
// 1 block/CU, 2 waves/SIMD, scales folded, setprio, 1 lite barrier/step.

#define LSTM_T 512
#define LSTM_IN 16
#define LSTM_H 64
#define LSTM_OUT 8
#define BT 4
#define HSTRIDE 80    // halves per batch row
#define HPSTR 320     // parity stride in halves = 4*HSTRIDE
#define XSTR 67       // float2 stride per slot row
#define XWSZ 2144     // 32*XSTR

#define L2E   1.44269504088896340736f
#define L2E2  2.88539008177792681472f

typedef _Float16 half8  __attribute__((ext_vector_type(8)));
typedef float    floatx4 __attribute__((ext_vector_type(4)));

static __device__ __forceinline__ float fast_rcp(float x) { return __builtin_amdgcn_rcpf(x); }
static __device__ __forceinline__ float fast_exp2(float x) { return __builtin_amdgcn_exp2f(x); }
static __device__ __forceinline__ float sigm2(float p) { return fast_rcp(1.0f + fast_exp2(-p)); }
static __device__ __forceinline__ void pin4(int4& v) {
    asm volatile("" : "+v"(v.x), "+v"(v.y), "+v"(v.z), "+v"(v.w));
}
static __device__ __forceinline__ void pinf4(float4& v) {
    asm volatile("" : "+v"(v.x), "+v"(v.y), "+v"(v.z), "+v"(v.w));
}
static __device__ __forceinline__ void lite_barrier() {
    asm volatile("s_waitcnt lgkmcnt(0)\n\ts_barrier" ::: "memory");
}
static __device__ __forceinline__ unsigned pk2h(float a, float b) {
    return __builtin_bit_cast(unsigned, __builtin_amdgcn_cvt_pkrtz(a, b));
}
static __device__ __forceinline__ half8 to_h8(float4 a, float4 b) {
    uint4 u = make_uint4(pk2h(a.x, a.y), pk2h(a.z, a.w), pk2h(b.x, b.y), pk2h(b.z, b.w));
    return __builtin_bit_cast(half8, u);
}
static __device__ __forceinline__ int4 cvt8h(float4 a, float4 b) {
    return __builtin_bit_cast(int4, to_h8(a, b));
}
static __device__ __forceinline__ float4 ld4(const float* p) {
    return *reinterpret_cast<const float4*>(p);
}
static __device__ __forceinline__ float4 scl4(float4 v, float s) {
    return make_float4(s * v.x, s * v.y, s * v.z, s * v.w);
}
static __device__ __forceinline__ float sel4(floatx4 v, bool r0, bool r1) {
    float lo = r0 ? v[1] : v[0];
    float hi = r0 ? v[3] : v[2];
    return r1 ? hi : lo;
}
// v_permlane32_swap_b32: x.hi <-> y.lo. With x=y=v on entry:
// exit x = low-half value on ALL lanes, y = high-half value on ALL lanes.
static __device__ __forceinline__ void pl32swap(float& x, float& y) {
    asm("v_permlane32_swap_b32 %0, %1" : "+v"(x), "+v"(y));
}

#define MF(A_, B_, C_) __builtin_amdgcn_mfma_f32_16x16x32_f16( \
        __builtin_bit_cast(half8, A_), (B_), (C_), 0, 0, 0)

__global__ __launch_bounds__(512, 2)
void lstm_mfma_kernel(const float* __restrict__ x,
                      const float* __restrict__ W_ih,
                      const float* __restrict__ W_hh,
                      const float* __restrict__ b_ih,
                      const float* __restrict__ b_hh,
                      const float* __restrict__ W_fc,
                      const float* __restrict__ b_fc,
                      float* __restrict__ out) {
    const int tid   = threadIdx.x;
    const int lane  = tid & 63;
    const int w     = tid >> 6;        // wave -> j-slice [8w, 8w+8)
    const int q     = lane >> 4;
    const int m     = lane & 15;
    const int b     = m & 3;           // real batch 0..3
    const int rho   = m >> 2;          // C reg select
    const bool r0   = (rho & 1) != 0;
    const bool r1   = (rho & 2) != 0;
    const int gh    = q >> 1;          // gate-half: 0 = f/i (lanes<32), 1 = g/o
    const int jj    = q & 1;
    const int jmine = 8 * w + 4 * jj + rho;
    const int bbase = blockIdx.x * BT;

    // gh=0: act1 = sigma(f); gh=1: act1 = L2E2*tanh(g)
    const float a1 = gh ? L2E2 : 0.0f;
    const float b1 = gh ? (-2.0f * L2E2) : 1.0f;

    __shared__ __align__(16)  float2   xwbuf[2][XWSZ];       // xw chunks
    __shared__ __align__(128) _Float16 hbuf[2][BT][HSTRIDE]; // h state, dbuf
    __shared__ __align__(16)  float    hfin[BT][LSTM_H];     // final h

    // ---- weights as pinned fp16 A-fragments (mixed-gate rows) ----
    // A row r: gate-half = r>>3, j-local = 4*((r>>2)&1) + (r&3).
    const int  ghr = m >> 3;
    const int  jl  = 4 * ((m >> 2) & 1) + (m & 3);
    const int  gFG = ghr ? 2 : 1;           // f=1, g=2
    const int  gIO = ghr ? 3 : 0;           // i=0, o=3
    const float sFG = ghr ? L2E2 : -L2E;
    const int growFG = gFG * 64 + 8 * w + jl;
    const int growIO = gIO * 64 + 8 * w + jl;
    int4 AhFG[2], AhIO[2], AxFG, AxIO;
    #pragma unroll
    for (int c = 0; c < 2; ++c) {
        const float* s1 = W_hh + growFG * LSTM_H + 32 * c + 8 * q;
        AhFG[c] = cvt8h(scl4(ld4(s1), sFG), scl4(ld4(s1 + 4), sFG));
        pin4(AhFG[c]);
        const float* s2 = W_hh + growIO * LSTM_H + 32 * c + 8 * q;
        AhIO[c] = cvt8h(scl4(ld4(s2), -L2E), scl4(ld4(s2 + 4), -L2E));
        pin4(AhIO[c]);
    }
    {
        float4 za = make_float4(0.f, 0.f, 0.f, 0.f);
        float4 xa = za, xb = za, ya = za, yb = za;
        if (q < 2) {
            const float* s1 = W_ih + growFG * LSTM_IN + 8 * q;
            xa = ld4(s1); xb = ld4(s1 + 4);
            const float* s2 = W_ih + growIO * LSTM_IN + 8 * q;
            ya = ld4(s2); yb = ld4(s2 + 4);
        }
        AxFG = cvt8h(scl4(xa, sFG), scl4(xb, sFG));   pin4(AxFG);
        AxIO = cvt8h(scl4(ya, -L2E), scl4(yb, -L2E)); pin4(AxIO);
    }
    // burst bias C-in (C rows 4q+p): gate-half = q>>1, j = 8w + 4*(q&1) + p
    float4 bFG4, bIO4;
    {
        const float scq = gh ? L2E2 : -L2E;
        const int gb1 = (gh ? 2 : 1) * 64 + 8 * w + 4 * jj;
        float4 bi = ld4(b_ih + gb1), bh = ld4(b_hh + gb1);
        bFG4 = make_float4(scq * (bi.x + bh.x), scq * (bi.y + bh.y),
                           scq * (bi.z + bh.z), scq * (bi.w + bh.w));
        pinf4(bFG4);
        const int gb2 = (gh ? 3 : 0) * 64 + 8 * w + 4 * jj;
        float4 ci = ld4(b_ih + gb2), ch = ld4(b_hh + gb2);
        bIO4 = make_float4(-L2E * (ci.x + ch.x), -L2E * (ci.y + ch.y),
                           -L2E * (ci.z + ch.z), -L2E * (ci.w + ch.w));
        pinf4(bIO4);
    }
    const floatx4 bFGv = __builtin_bit_cast(floatx4, bFG4);
    const floatx4 bIOv = __builtin_bit_cast(floatx4, bIO4);

    float4 zc4 = make_float4(0.f, 0.f, 0.f, 0.f);
    pinf4(zc4);
    const floatx4 zc = __builtin_bit_cast(floatx4, zc4);

    // ---- LDS pointers ----
    const float2* xwr = &xwbuf[0][(b * 2 + gh) * XSTR + jmine];
    float2*       xww = &xwbuf[0][((m >> 2) * 8 + (m & 3) * 2 + gh) * XSTR
                                  + 8 * w + 4 * jj];
    const _Float16* hrp = &hbuf[0][b][8 * q];
    _Float16*       hwp = &hbuf[0][b][jmine];

    // ---- zero hbuf[0] (h_{-1}=0): 4 rows * 80 halves = 160 dwords ----
    if (tid < 160) reinterpret_cast<int*>(&hbuf[0][0][0])[tid] = 0;

    // ---- burst x pointer: lane covers (b=m&3, t-in-chunk=m>>2) ----
    const float* xpb = x + (size_t)(bbase + b) * LSTM_T * LSTM_IN
                         + (size_t)(m >> 2) * LSTM_IN + 8 * q;
    float4 Xb0 = make_float4(0.f, 0.f, 0.f, 0.f), Xb1 = Xb0;
    if (q < 2) { Xb0 = ld4(xpb); Xb1 = ld4(xpb + 4); }   // chunk 0

#define WX(BUF, P_) xww[(BUF) * XWSZ + (P_)] = make_float2(aFGx[P_], aIOx[P_]);

    // ---- prologue: chunk0 -> buf0 ----
    floatx4 aFGx, aIOx;
    half8 xfb;
    {
        half8 x0 = to_h8(Xb0, Xb1);
        aFGx = MF(AxFG, x0, bFGv);
        aIOx = MF(AxIO, x0, bIOv);
        WX(0, 0) WX(0, 1) WX(0, 2) WX(0, 3)
    }
    if (q < 2) {   // x for chunk 1
        Xb0 = ld4(xpb + 4 * LSTM_IN);
        Xb1 = ld4(xpb + 4 * LSTM_IN + 4);
    }
    __syncthreads();   // hbuf zeros + chunk0 visible

    float2 xwc = xwr[0];             // k=0, buf0
    float cs = 0.0f, hreg = 0.0f;    // cs = L2E2*c, canonical on ALL lanes

// PK = hbuf parity (literal), KN = next step's k (literal),
// NCB = next step's chunk buf (literal). __VA_ARGS__ = spread burst op.
#define STEP_CORE(PK, KN, NCB, ...)                                             \
    {                                                                           \
        half8 bh0 = *reinterpret_cast<const half8*>(hrp + (PK) * HPSTR);        \
        half8 bh1 = *reinterpret_cast<const half8*>(hrp + (PK) * HPSTR + 32);   \
        __VA_ARGS__                                                             \
        float2 xwn = xwr[(NCB) * XWSZ + (KN) * 8 * XSTR];                       \
        floatx4 accFG = MF(AhFG[0], bh0, zc);                                   \
        floatx4 accIO = MF(AhIO[0], bh0, zc);                                   \
        accFG = MF(AhFG[1], bh1, accFG);                                        \
        accIO = MF(AhIO[1], bh1, accIO);                                        \
        __builtin_amdgcn_s_setprio(1);                                          \
        float u1 = sel4(accFG, r0, r1) + xwc.x;                                 \
        float e1 = fast_exp2(u1);                                               \
        float u2 = sel4(accIO, r0, r1) + xwc.y;                                 \
        float act1 = fmaf(b1, fast_rcp(1.0f + e1), a1);                         \
        float e2 = fast_exp2(u2);                                               \
        float act2 = fast_rcp(1.0f + e2);                                       \
        /* permlane double-role: fsel/gsel/isel/osel canonical on ALL lanes */  \
        float fsel = act1, gsel = act1;                                         \
        pl32swap(fsel, gsel);   /* fsel = sigma(f), gsel = L2E2*tanh(g) */      \
        float isel = act2, osel = act2;                                         \
        pl32swap(isel, osel);   /* isel = sigma(i), osel = sigma(o) */          \
        cs = fmaf(fsel, cs, isel * gsel);                                       \
        float E  = fast_exp2(cs);                                               \
        float r_ = fast_rcp(1.0f + E);                                          \
        float n2o = -2.0f * osel;                                               \
        hreg = fmaf(n2o, r_, osel);  /* o * tanh(c) */                          \
        hwp[((PK) ^ 1) * HPSTR] = (_Float16)hreg;  /* pair lanes: same addr, */ \
        __builtin_amdgcn_s_setprio(0);             /* same value -> merge */    \
        lite_barrier();                                                         \
        xwc = xwn;                                                              \
    }

    for (int t8 = 0; t8 < LSTM_T; t8 += 8) {
        const bool mA = t8 + 4  < LSTM_T;   // produce chunk c+1 (buf1)
        const bool mB = t8 + 8  < LSTM_T;   // produce chunk c+2 (buf0)
        const bool xB = t8 + 12 < LSTM_T;   // load x for chunk c+3
        // chunk A: consume buf0, produce buf1
        STEP_CORE(0, 1, 0,
            { if (mA) { xfb = to_h8(Xb0, Xb1); aFGx = MF(AxFG, xfb, bFGv); } })
        STEP_CORE(1, 2, 0, { if (mA) { aIOx = MF(AxIO, xfb, bIOv); } })
        STEP_CORE(0, 3, 0, { if (mA) { WX(1, 0) WX(1, 1) } })
        STEP_CORE(1, 0, 1, { if (mA) { WX(1, 2) WX(1, 3) }
            if (q < 2 && mB) { Xb0 = ld4(xpb + (size_t)(t8 + 8) * LSTM_IN);
                               Xb1 = ld4(xpb + (size_t)(t8 + 8) * LSTM_IN + 4); } })
        // chunk B: consume buf1, produce buf0
        STEP_CORE(0, 1, 1,
            { if (mB) { xfb = to_h8(Xb0, Xb1); aFGx = MF(AxFG, xfb, bFGv); } })
        STEP_CORE(1, 2, 1, { if (mB) { aIOx = MF(AxIO, xfb, bIOv); } })
        STEP_CORE(0, 3, 1, { if (mB) { WX(0, 0) WX(0, 1) } })
        STEP_CORE(1, 0, 0, { if (mB) { WX(0, 2) WX(0, 3) }
            if (q < 2 && xB) { Xb0 = ld4(xpb + (size_t)(t8 + 12) * LSTM_IN);
                               Xb1 = ld4(xpb + (size_t)(t8 + 12) * LSTM_IN + 4); } })
    }
#undef STEP_CORE
#undef WX

    // ---- final h (fp32) -> LDS, then FC + sigmoid ----
    hfin[b][jmine] = hreg;   // all lanes canonical (pair lanes same value)
    __syncthreads();

    if (tid < BT * LSTM_OUT) {
        int bb = tid >> 3, o = tid & 7;
        float s = b_fc[o];
        #pragma unroll
        for (int j4 = 0; j4 < LSTM_H / 4; ++j4) {
            float4 wv = ld4(W_fc + o * LSTM_H + 4 * j4);
            float4 hv = *reinterpret_cast<const float4*>(&hfin[bb][4 * j4]);
            s = fmaf(wv.x, hv.x, s);
            s = fmaf(wv.y, hv.y, s);
            s = fmaf(wv.z, hv.z, s);
            s = fmaf(wv.w, hv.w, s);
        }
        out[(size_t)(bbase + bb) * LSTM_OUT + o] = sigm2(s * L2E);
    }
}

extern "C" void kernel_launch(void* const* d_in, const int* in_sizes, int n_in,
                              void* d_out, int out_size, void* d_ws, size_t ws_size,
                              hipStream_t stream) {
    const float* x    = (const float*)d_in[0];
    const float* W_ih = (const float*)d_in[1];
    const float* W_hh = (const float*)d_in[2];
    const float* b_ih = (const float*)d_in[3];
    const float* b_hh = (const float*)d_in[4];
    const float* W_fc = (const float*)d_in[5];
    const float* b_fc = (const float*)d_in[6];
    float* out = (float*)d_out;

    lstm_mfma_kernel<<<1024 / BT, 512, 0, stream>>>(
        x, W_ih, W_hh, b_ih, b_hh, W_fc, b_fc, out);
}